// Round 6
// baseline (204.392 us; speedup 1.0000x reference)
//
#include <hip/hip_runtime.h>

static constexpr int T_LEN = 512;

typedef float v2f __attribute__((ext_vector_type(2)));

__device__ __forceinline__ float fsigm(float x) {
    return __builtin_amdgcn_rcpf(1.0f + __expf(-x));
}
__device__ __forceinline__ float ftanh(float x) {
    return 1.0f - 2.0f * __builtin_amdgcn_rcpf(1.0f + __expf(2.0f * x));
}
template <int CTRL>
__device__ __forceinline__ float rotf(float v) {
    return __builtin_bit_cast(float,
        __builtin_amdgcn_mov_dpp(__builtin_bit_cast(int, v), CTRL, 0xf, 0xf, true));
}

// MERGED-ROLE wave: lanes (j=lane&15, role=(lane>>4)&1, bq=lane>>5).
//   role0 rows: layer-0 for batch b; role1 rows: layer-1 for the SAME batch,
//   skewed one step behind. h0 handoff = ONE shfl_xor(hs,16) per step.
// NO LDS, NO barriers, no role imbalance: both roles execute the same
// instruction stream (packed systolic dots via DPP row_ror + v_pk_fma_f32),
// with role-dependent operands spliced by cndmask.
//   A-dot (16 iters, rot1-advance): role0 pair=(x_lo,x_hi); role1 pair=(u,h).
//   B-dot (8 iters, rot2-advance):  role0 pair=(h,rot1 h);  role1 weights=0.
__global__ __launch_bounds__(256, 1) void gru2_merged(
    const float* __restrict__ x,
    const float* __restrict__ Wih0, const float* __restrict__ Whh0,
    const float* __restrict__ bih0, const float* __restrict__ bhh0,
    const float* __restrict__ Wih1, const float* __restrict__ Whh1,
    const float* __restrict__ bih1, const float* __restrict__ bhh1,
    const float* __restrict__ fcw,  const float* __restrict__ fcb,
    float* __restrict__ out)
{
    const int tid  = threadIdx.x;
    const int lane = tid & 63;
    const int j    = lane & 15;          // unit index
    const int role = (lane >> 4) & 1;    // 0 = layer-0, 1 = layer-1
    const int bq   = lane >> 5;          // batch within wave (0/1)
    const int b    = blockIdx.x * 8 + (tid >> 6) * 2 + bq;

    // rotation-direction probes (robust to ror encoding/direction)
    const int d1 = (((int)rotf<0x121>((float)j)) - j) & 15;
    const int d2 = (((int)rotf<0x122>((float)j)) - j) & 15;

    // ---- per-lane packed weights ----
    // WA[g][m]: role0 = (Wih0[row, cm], Wih0[row, 16+cm])
    //           role1 = (Wih1[row, cm], Whh1[row, cm]),  cm=(j+m*d1)&15
    // WB[g][k]: role0 = (Whh0[row, e0], Whh0[row, e1]),
    //           e0=(j+k*d2)&15, e1=(j+d1+k*d2)&15 ; role1 = (0,0)
    v2f WA[3][16];
    v2f WB[3][8];
    float b_r, b_z, b_in, b_hn;
#pragma unroll
    for (int g = 0; g < 3; ++g) {
        const int row = g * 16 + j;
#pragma unroll
        for (int m = 0; m < 16; ++m) {
            const int cm = (j + m * d1) & 15;
            if (role) {
                WA[g][m].x = Wih1[row * 16 + cm];
                WA[g][m].y = Whh1[row * 16 + cm];
            } else {
                WA[g][m].x = Wih0[row * 32 + cm];
                WA[g][m].y = Wih0[row * 32 + 16 + cm];
            }
        }
#pragma unroll
        for (int k = 0; k < 8; ++k) {
            if (role) {
                WB[g][k].x = 0.f; WB[g][k].y = 0.f;
            } else {
                const int e0 = (j + k * d2) & 15;
                const int e1 = (j + d1 + k * d2) & 15;
                WB[g][k].x = Whh0[row * 16 + e0];
                WB[g][k].y = Whh0[row * 16 + e1];
            }
        }
    }
    if (role) {
        b_r  = bih1[j]      + bhh1[j];
        b_z  = bih1[16 + j] + bhh1[16 + j];
        b_in = bih1[32 + j];
        b_hn = bhh1[32 + j];
    } else {
        b_r  = bih0[j]      + bhh0[j];
        b_z  = bih0[16 + j] + bhh0[16 + j];
        b_in = bih0[32 + j];
        b_hn = bhh0[32 + j];
    }

    float hs = 0.f;   // role0: h0_j ; role1: h1_j (distributed state)

    const float* xbase = x + (size_t)b * T_LEN * 32;

    // 4-deep lane-distributed x ring (role1 lanes load duplicate addresses —
    // same cache lines as their sibling row, negligible cost, keeps issue
    // uniform). Slot k holds step (i & ~3) + k.
    float xl[4], xh[4];
#pragma unroll
    for (int k = 0; k < 4; ++k) {
        xl[k] = xbase[k * 32 + j];
        xh[k] = xbase[k * 32 + 16 + j];
    }

    auto step = [&](int i, int slot) {
        // sibling-row h BEFORE this step's update:
        // role1 lanes receive u = h0[i-1]; role0 lanes receive (unused) h1.
        const float us = __shfl_xor(hs, 16, 64);

        const float x0 = xl[slot], x1 = xh[slot];
        const int t4 = (i + 4 < T_LEN) ? (i + 4) : (T_LEN - 1);
        xl[slot] = xbase[t4 * 32 + j];
        xh[slot] = xbase[t4 * 32 + 16 + j];

        // splice role-dependent A-operand
        v2f pA;
        pA.x = role ? us : x0;
        pA.y = role ? hs : x1;
        v2f pB;
        pB.x = hs;
        pB.y = rotf<0x121>(hs);

        v2f aA0 = {0.f,0.f}, aA1 = {0.f,0.f}, aA2 = {0.f,0.f};
        v2f aB0 = {0.f,0.f}, aB1 = {0.f,0.f}, aB2 = {0.f,0.f};
#pragma unroll
        for (int m = 0; m < 16; ++m) {
            aA0 = __builtin_elementwise_fma(WA[0][m], pA, aA0);
            aA1 = __builtin_elementwise_fma(WA[1][m], pA, aA1);
            aA2 = __builtin_elementwise_fma(WA[2][m], pA, aA2);
            if (m < 8) {
                aB0 = __builtin_elementwise_fma(WB[0][m], pB, aB0);
                aB1 = __builtin_elementwise_fma(WB[1][m], pB, aB1);
                aB2 = __builtin_elementwise_fma(WB[2][m], pB, aB2);
                if (m < 7) { pB.x = rotf<0x122>(pB.x); pB.y = rotf<0x122>(pB.y); }
            }
            if (m < 15) { pA.x = rotf<0x121>(pA.x); pA.y = rotf<0x121>(pA.y); }
        }

        // r/z gates: total pre-activation is uniform (role1's aB = 0)
        const float pre_r = aA0.x + aA0.y + aB0.x + aB0.y + b_r;
        const float pre_z = aA1.x + aA1.y + aB1.x + aB1.y + b_z;
        // n gate needs input-part and hidden-part separated:
        //   role0: xn = aA2.x + aA2.y            hn = aB2.x + aB2.y
        //   role1: xn = aA2.x                    hn = aA2.y (+ aB2 == 0)
        const float xn_p = aA2.x + (role ? 0.f : aA2.y);
        const float hn_p = (role ? aA2.y : 0.f) + aB2.x + aB2.y;

        const float r = fsigm(pre_r);
        const float z = fsigm(pre_z);
        const float n = ftanh(xn_p + b_in + r * (hn_p + b_hn));
        hs = fmaf(z, hs - n, n);
    };

    // iter 0: role0 computes h0[0]; role1's result is garbage -> reset to 0
    step(0, 0);
    hs = role ? 0.f : hs;

    // iters 1..512: role0 does t=i (phantom at i=512, harmless);
    // role1 does t=i-1. After iter 512 role1 holds h1[511].
#pragma unroll 1
    for (int i = 1; i <= T_LEN; ++i)
        step(i, i & 3);

    // ---- FC on final h1 (role1 rows hold it distributed) ----
    if (role) {
        float p = fcw[j] * hs;
        p += __shfl_xor(p, 1);
        p += __shfl_xor(p, 2);
        p += __shfl_xor(p, 4);
        p += __shfl_xor(p, 8);
        if (j == 0) out[b] = p + fcb[0];
    }
}

extern "C" void kernel_launch(void* const* d_in, const int* in_sizes, int n_in,
                              void* d_out, int out_size, void* d_ws, size_t ws_size,
                              hipStream_t stream) {
    const float* x    = (const float*)d_in[0];
    const float* Wih0 = (const float*)d_in[1];
    const float* Whh0 = (const float*)d_in[2];
    const float* bih0 = (const float*)d_in[3];
    const float* bhh0 = (const float*)d_in[4];
    const float* Wih1 = (const float*)d_in[5];
    const float* Whh1 = (const float*)d_in[6];
    const float* bih1 = (const float*)d_in[7];
    const float* bhh1 = (const float*)d_in[8];
    const float* fcw  = (const float*)d_in[9];
    const float* fcb  = (const float*)d_in[10];

    // 2048 batches, 2 per wave (both layers in-wave), 4 waves/block
    // -> 256 blocks x 256 threads (1 block/CU, 1024 waves total)
    gru2_merged<<<256, 256, 0, stream>>>(x, Wih0, Whh0, bih0, bhh0,
                                         Wih1, Whh1, bih1, bhh1, fcw, fcb,
                                         (float*)d_out);
}